// Round 1
// baseline (1041.324 us; speedup 1.0000x reference)
//
#include <hip/hip_runtime.h>
#include <hip/hip_bf16.h>
#include <math.h>

// Problem constants (fixed by the reference).
#define DEPTHC 2
#define DIMD   256
#define MLPD   1024
#define BB     2
#define NN     2048
#define HH     8
#define HD     32
#define ROWS   (BB * NN)   // 4096 token rows

// ---------------------------------------------------------------------------
// LayerNorm: one wave (64 lanes) per 256-element row; 4 rows per 256-thr block.
// ---------------------------------------------------------------------------
__global__ __launch_bounds__(256) void ln_kernel(
    const float* __restrict__ x, const float* __restrict__ g,
    const float* __restrict__ bta, float* __restrict__ y)
{
    const int wave = threadIdx.x >> 6;
    const int lane = threadIdx.x & 63;
    const int row  = blockIdx.x * 4 + wave;
    const float* xr = x + (size_t)row * DIMD;

    float v[4];
    float s = 0.f, sq = 0.f;
#pragma unroll
    for (int i = 0; i < 4; ++i) {
        v[i] = xr[lane + 64 * i];
        s  += v[i];
        sq += v[i] * v[i];
    }
#pragma unroll
    for (int off = 32; off > 0; off >>= 1) {
        s  += __shfl_down(s,  off, 64);
        sq += __shfl_down(sq, off, 64);
    }
    s  = __shfl(s,  0, 64);
    sq = __shfl(sq, 0, 64);

    const float mean = s * (1.f / DIMD);
    const float var  = sq * (1.f / DIMD) - mean * mean;
    const float rstd = rsqrtf(var + 1e-5f);

    float* yr = y + (size_t)row * DIMD;
#pragma unroll
    for (int i = 0; i < 4; ++i) {
        const int c = lane + 64 * i;
        yr[c] = (v[i] - mean) * rstd * g[c] + bta[c];
    }
}

// ---------------------------------------------------------------------------
// Generic f32 GEMM: C[M,N] = epilogue(A[M,K] @ W[K,N] + bias (+R) (gelu?))
// 64x64 tile, BK=16, 256 threads, 4x4 micro-tile per thread.
// ---------------------------------------------------------------------------
template <bool GELU, bool RES>
__global__ __launch_bounds__(256) void gemm64(
    const float* __restrict__ A, const float* __restrict__ W,
    const float* __restrict__ bias, const float* __restrict__ R,
    float* __restrict__ C, int M, int N, int K)
{
    __shared__ float As[16][64];   // transposed A tile: As[k][m]
    __shared__ float Ws[16][64];

    const int tid = threadIdx.x;
    const int m0  = blockIdx.y * 64;
    const int n0  = blockIdx.x * 64;

    const int am = tid >> 2;           // 0..63  (A tile row)
    const int ak = (tid & 3) << 2;     // 0,4,8,12
    const int wk = tid >> 4;           // 0..15  (W tile row)
    const int wn = (tid & 15) << 2;    // 0..60
    const int tm = (tid >> 4) << 2;    // micro-tile row base
    const int tn = (tid & 15) << 2;    // micro-tile col base

    float acc[4][4] = {};

    for (int k0 = 0; k0 < K; k0 += 16) {
        const float4 a4 = *(const float4*)&A[(size_t)(m0 + am) * K + k0 + ak];
        As[ak + 0][am] = a4.x;
        As[ak + 1][am] = a4.y;
        As[ak + 2][am] = a4.z;
        As[ak + 3][am] = a4.w;
        *(float4*)&Ws[wk][wn] = *(const float4*)&W[(size_t)(k0 + wk) * N + n0 + wn];
        __syncthreads();

#pragma unroll
        for (int kk = 0; kk < 16; ++kk) {
            const float4 a = *(const float4*)&As[kk][tm];
            const float4 w = *(const float4*)&Ws[kk][tn];
            const float av[4] = {a.x, a.y, a.z, a.w};
            const float wv[4] = {w.x, w.y, w.z, w.w};
#pragma unroll
            for (int i = 0; i < 4; ++i)
#pragma unroll
                for (int j = 0; j < 4; ++j)
                    acc[i][j] += av[i] * wv[j];
        }
        __syncthreads();
    }

#pragma unroll
    for (int i = 0; i < 4; ++i) {
        float4 outv;
        float* po = (float*)&outv;
        const size_t crow = (size_t)(m0 + tm + i) * N + n0 + tn;
#pragma unroll
        for (int j = 0; j < 4; ++j) {
            float vv = acc[i][j] + bias[n0 + tn + j];
            if (RES)  vv += R[crow + j];
            if (GELU) vv = 0.5f * vv * (1.f + erff(vv * 0.70710678118f));
            po[j] = vv;
        }
        *(float4*)&C[crow] = outv;
    }
}

// ---------------------------------------------------------------------------
// Flash-style attention. Grid: (N/64, B*H). Block: 1 wave (64 threads).
// lane = query row. K/V staged in LDS in 64-key tiles; online softmax over
// 16-key subtiles (keeps score array fully in registers).
// qkv layout: [B, N, 3*DIM] with q at col h*32, k at 256+h*32, v at 512+h*32.
// ---------------------------------------------------------------------------
__global__ __launch_bounds__(64) void attn_kernel(
    const float* __restrict__ qkv, float* __restrict__ o)
{
    const int bh   = blockIdx.y;
    const int b    = bh >> 3;
    const int h    = bh & 7;
    const int lane = threadIdx.x;
    const int r    = blockIdx.x * 64 + lane;
    const float scale = 0.17677669529663689f;  // 32^-0.5

    const float* base = qkv + (size_t)b * NN * (3 * DIMD);
    const float* qp   = base + (size_t)r * (3 * DIMD) + h * HD;

    float qr[HD];
#pragma unroll
    for (int d = 0; d < HD; ++d) qr[d] = qp[d] * scale;

    float oacc[HD] = {};
    float mval = -1e30f, lsum = 0.f;

    __shared__ float Ks[64][HD];
    __shared__ float Vs[64][HD];

    for (int kt = 0; kt < NN / 64; ++kt) {
        const float* krow = base + (size_t)(kt * 64 + lane) * (3 * DIMD) + h * HD;
#pragma unroll
        for (int i = 0; i < 8; ++i) {
            ((float4*)Ks[lane])[i] = ((const float4*)(krow + 256))[i];
            ((float4*)Vs[lane])[i] = ((const float4*)(krow + 512))[i];
        }
        __syncthreads();

#pragma unroll 1
        for (int j0 = 0; j0 < 64; j0 += 16) {
            float s[16];
            float tmax = -1e30f;
#pragma unroll
            for (int jj = 0; jj < 16; ++jj) {
                float acc = 0.f;
#pragma unroll
                for (int d = 0; d < HD; ++d) acc += qr[d] * Ks[j0 + jj][d];
                s[jj] = acc;
                tmax = fmaxf(tmax, acc);
            }
            const float mnew  = fmaxf(mval, tmax);
            const float alpha = __expf(mval - mnew);
            lsum *= alpha;
#pragma unroll
            for (int d = 0; d < HD; ++d) oacc[d] *= alpha;
#pragma unroll
            for (int jj = 0; jj < 16; ++jj) {
                const float p = __expf(s[jj] - mnew);
                lsum += p;
#pragma unroll
                for (int d = 0; d < HD; ++d) oacc[d] += p * Vs[j0 + jj][d];
            }
            mval = mnew;
        }
        __syncthreads();
    }

    const float inv = 1.f / lsum;
    float* op = o + ((size_t)(b * NN + r)) * DIMD + h * HD;
#pragma unroll
    for (int d = 0; d < HD; ++d) op[d] = oacc[d] * inv;
}

// ---------------------------------------------------------------------------
// Launch: only the LAST layer (i = DEPTH-1) matters — the reference never
// feeds `out` back into `x`, so earlier layers' outputs are discarded.
// ---------------------------------------------------------------------------
extern "C" void kernel_launch(void* const* d_in, const int* in_sizes, int n_in,
                              void* d_out, int out_size, void* d_ws, size_t ws_size,
                              hipStream_t stream)
{
    const int L = DEPTHC - 1;  // last layer only
    const float* x     = (const float*)d_in[0];
    const float* ln1_g = (const float*)d_in[1]  + L * DIMD;
    const float* ln1_b = (const float*)d_in[2]  + L * DIMD;
    const float* Wqkv  = (const float*)d_in[3]  + (size_t)L * DIMD * 3 * DIMD;
    const float* bqkv  = (const float*)d_in[4]  + L * 3 * DIMD;
    const float* Wo    = (const float*)d_in[5]  + (size_t)L * DIMD * DIMD;
    const float* bo    = (const float*)d_in[6]  + L * DIMD;
    const float* ln2_g = (const float*)d_in[7]  + L * DIMD;
    const float* ln2_b = (const float*)d_in[8]  + L * DIMD;
    const float* W1    = (const float*)d_in[9]  + (size_t)L * DIMD * MLPD;
    const float* b1    = (const float*)d_in[10] + L * MLPD;
    const float* W2    = (const float*)d_in[11] + (size_t)L * MLPD * DIMD;
    const float* b2    = (const float*)d_in[12] + L * DIMD;
    float* out = (float*)d_out;

    // Workspace layout (floats):
    float* y   = (float*)d_ws;                  // [4096,256]  (reused for z)
    float* qkv = y   + (size_t)ROWS * DIMD;     // [4096,768]
    float* o   = qkv + (size_t)ROWS * 3 * DIMD; // [4096,256]
    float* a   = o   + (size_t)ROWS * DIMD;     // [4096,256]
    float* m1  = a   + (size_t)ROWS * DIMD;     // [4096,1024]

    // 1) y = LN1(x)
    ln_kernel<<<ROWS / 4, 256, 0, stream>>>(x, ln1_g, ln1_b, y);

    // 2) qkv = y @ Wqkv + bqkv
    gemm64<false, false><<<dim3(3 * DIMD / 64, ROWS / 64), 256, 0, stream>>>(
        y, Wqkv, bqkv, nullptr, qkv, ROWS, 3 * DIMD, DIMD);

    // 3) o = attention(q, k, v)
    attn_kernel<<<dim3(NN / 64, BB * HH), 64, 0, stream>>>(qkv, o);

    // 4) a = o @ Wo + bo + x
    gemm64<false, true><<<dim3(DIMD / 64, ROWS / 64), 256, 0, stream>>>(
        o, Wo, bo, x, a, ROWS, DIMD, DIMD);

    // 5) z = LN2(a)  (reuse y buffer)
    ln_kernel<<<ROWS / 4, 256, 0, stream>>>(a, ln2_g, ln2_b, y);

    // 6) m1 = gelu(z @ W1 + b1)
    gemm64<true, false><<<dim3(MLPD / 64, ROWS / 64), 256, 0, stream>>>(
        y, W1, b1, nullptr, m1, ROWS, MLPD, DIMD);

    // 7) out = m1 @ W2 + b2 + a
    gemm64<false, true><<<dim3(DIMD / 64, ROWS / 64), 256, 0, stream>>>(
        m1, W2, b2, a, out, ROWS, DIMD, MLPD);
}

// Round 2
// 667.436 us; speedup vs baseline: 1.5602x; 1.5602x over previous
//
#include <hip/hip_runtime.h>
#include <hip/hip_bf16.h>
#include <math.h>

// Problem constants (fixed by the reference).
#define DEPTHC 2
#define DIMD   256
#define MLPD   1024
#define BB     2
#define NN     2048
#define HH     8
#define HD     32
#define ROWS   (BB * NN)   // 4096 token rows

// ---------------------------------------------------------------------------
// LayerNorm: one wave (64 lanes) per 256-element row; 4 rows per 256-thr block.
// ---------------------------------------------------------------------------
__global__ __launch_bounds__(256) void ln_kernel(
    const float* __restrict__ x, const float* __restrict__ g,
    const float* __restrict__ bta, float* __restrict__ y)
{
    const int wave = threadIdx.x >> 6;
    const int lane = threadIdx.x & 63;
    const int row  = blockIdx.x * 4 + wave;
    const float* xr = x + (size_t)row * DIMD;

    float v[4];
    float s = 0.f, sq = 0.f;
#pragma unroll
    for (int i = 0; i < 4; ++i) {
        v[i] = xr[lane + 64 * i];
        s  += v[i];
        sq += v[i] * v[i];
    }
#pragma unroll
    for (int off = 32; off > 0; off >>= 1) {
        s  += __shfl_down(s,  off, 64);
        sq += __shfl_down(sq, off, 64);
    }
    s  = __shfl(s,  0, 64);
    sq = __shfl(sq, 0, 64);

    const float mean = s * (1.f / DIMD);
    const float var  = sq * (1.f / DIMD) - mean * mean;
    const float rstd = rsqrtf(var + 1e-5f);

    float* yr = y + (size_t)row * DIMD;
#pragma unroll
    for (int i = 0; i < 4; ++i) {
        const int c = lane + 64 * i;
        yr[c] = (v[i] - mean) * rstd * g[c] + bta[c];
    }
}

// ---------------------------------------------------------------------------
// Generic f32 GEMM: C[M,N] = epilogue(A[M,K] @ W[K,N] + bias (+R) (gelu?))
// 64x64 tile, BK=16, 256 threads, 4x4 micro-tile per thread.
// ---------------------------------------------------------------------------
template <bool GELU, bool RES>
__global__ __launch_bounds__(256) void gemm64(
    const float* __restrict__ A, const float* __restrict__ W,
    const float* __restrict__ bias, const float* __restrict__ R,
    float* __restrict__ C, int M, int N, int K)
{
    __shared__ float As[16][64];   // transposed A tile: As[k][m]
    __shared__ float Ws[16][64];

    const int tid = threadIdx.x;
    const int m0  = blockIdx.y * 64;
    const int n0  = blockIdx.x * 64;

    const int am = tid >> 2;           // 0..63  (A tile row)
    const int ak = (tid & 3) << 2;     // 0,4,8,12
    const int wk = tid >> 4;           // 0..15  (W tile row)
    const int wn = (tid & 15) << 2;    // 0..60
    const int tm = (tid >> 4) << 2;    // micro-tile row base
    const int tn = (tid & 15) << 2;    // micro-tile col base

    float acc[4][4] = {};

    for (int k0 = 0; k0 < K; k0 += 16) {
        const float4 a4 = *(const float4*)&A[(size_t)(m0 + am) * K + k0 + ak];
        As[ak + 0][am] = a4.x;
        As[ak + 1][am] = a4.y;
        As[ak + 2][am] = a4.z;
        As[ak + 3][am] = a4.w;
        *(float4*)&Ws[wk][wn] = *(const float4*)&W[(size_t)(k0 + wk) * N + n0 + wn];
        __syncthreads();

#pragma unroll
        for (int kk = 0; kk < 16; ++kk) {
            const float4 a = *(const float4*)&As[kk][tm];
            const float4 w = *(const float4*)&Ws[kk][tn];
            const float av[4] = {a.x, a.y, a.z, a.w};
            const float wv[4] = {w.x, w.y, w.z, w.w};
#pragma unroll
            for (int i = 0; i < 4; ++i)
#pragma unroll
                for (int j = 0; j < 4; ++j)
                    acc[i][j] += av[i] * wv[j];
        }
        __syncthreads();
    }

#pragma unroll
    for (int i = 0; i < 4; ++i) {
        float4 outv;
        float* po = (float*)&outv;
        const size_t crow = (size_t)(m0 + tm + i) * N + n0 + tn;
#pragma unroll
        for (int j = 0; j < 4; ++j) {
            float vv = acc[i][j] + bias[n0 + tn + j];
            if (RES)  vv += R[crow + j];
            if (GELU) vv = 0.5f * vv * (1.f + erff(vv * 0.70710678118f));
            po[j] = vv;
        }
        *(float4*)&C[crow] = outv;
    }
}

// ---------------------------------------------------------------------------
// Flash attention, key-split for occupancy.
// Grid: (N/64 q-tiles, B*H). Block: 512 threads = 8 waves.
// All 8 waves process the SAME 64 queries (lane = query); wave w processes
// keys [w*256, (w+1)*256) with its own online-softmax state in registers.
// K/V rows read straight from global (wave-broadcast addresses; L2-hot).
// Partials merged by a 3-level tree through LDS (padded rows, conflict-free).
// qkv layout: [B, N, 3*DIM]; q at col h*32, k at 256+h*32, v at 512+h*32.
// ---------------------------------------------------------------------------
#define KV_WAVES 8
#define KEYS_PER_WAVE (NN / KV_WAVES)   // 256

__global__ __launch_bounds__(512, 4) void attn_kernel(
    const float* __restrict__ qkv, float* __restrict__ o)
{
    const int tid  = threadIdx.x;
    const int w    = tid >> 6;        // wave id, 0..7
    const int lane = tid & 63;        // query within tile
    const int bh   = blockIdx.y;
    const int b    = bh >> 3;
    const int h    = bh & 7;
    const int r    = blockIdx.x * 64 + lane;   // query row within batch b
    const float scale = 0.17677669529663689f;  // 32^-0.5

    const float* base = qkv + (size_t)b * NN * (3 * DIMD);

    // Load and pre-scale this lane's query (32 floats = 8 float4).
    float4 qr[8];
    {
        const float4* qp = (const float4*)(base + (size_t)r * (3 * DIMD) + h * HD);
#pragma unroll
        for (int i = 0; i < 8; ++i) {
            float4 t = qp[i];
            t.x *= scale; t.y *= scale; t.z *= scale; t.w *= scale;
            qr[i] = t;
        }
    }

    float4 oacc[8] = {};
    float mval = -1e30f, lsum = 0.f;

    // ---- main loop over this wave's 256 keys, in 16-key subtiles ----
#pragma unroll 1
    for (int t16 = 0; t16 < KEYS_PER_WAVE / 16; ++t16) {
        const int kbase = w * KEYS_PER_WAVE + t16 * 16;

        float s[16];
        float tmax = -1e30f;
#pragma unroll 4
        for (int jj = 0; jj < 16; ++jj) {
            const float4* kp =
                (const float4*)(base + (size_t)(kbase + jj) * (3 * DIMD) + DIMD + h * HD);
            float acc = 0.f;
#pragma unroll
            for (int i = 0; i < 8; ++i) {
                const float4 k4 = kp[i];
                acc += qr[i].x * k4.x + qr[i].y * k4.y + qr[i].z * k4.z + qr[i].w * k4.w;
            }
            s[jj] = acc;
            tmax = fmaxf(tmax, acc);
        }

        const float mnew  = fmaxf(mval, tmax);
        const float alpha = __expf(mval - mnew);
        lsum *= alpha;
#pragma unroll
        for (int i = 0; i < 8; ++i) {
            oacc[i].x *= alpha; oacc[i].y *= alpha;
            oacc[i].z *= alpha; oacc[i].w *= alpha;
        }

#pragma unroll 4
        for (int jj = 0; jj < 16; ++jj) {
            const float p = __expf(s[jj] - mnew);
            lsum += p;
            const float4* vp =
                (const float4*)(base + (size_t)(kbase + jj) * (3 * DIMD) + 2 * DIMD + h * HD);
#pragma unroll
            for (int i = 0; i < 8; ++i) {
                const float4 v4 = vp[i];
                oacc[i].x += p * v4.x; oacc[i].y += p * v4.y;
                oacc[i].z += p * v4.z; oacc[i].w += p * v4.w;
            }
        }
        mval = mnew;
    }

    // ---- tree merge of the 8 per-wave partials (3 rounds) ----
    // Row padded to 36 floats: float4 accesses land 2-way per 16-lane phase
    // (free per m136); 4*64*36*4 + 2*4*64*4 = 38.9 KB LDS.
    __shared__ float pm[4][64];
    __shared__ float pl[4][64];
    __shared__ float po[4][64][36];

#pragma unroll 1
    for (int stride = 4; stride >= 1; stride >>= 1) {
        if (w >= stride && w < 2 * stride) {
            const int slot = w - stride;
            pm[slot][lane] = mval;
            pl[slot][lane] = lsum;
#pragma unroll
            for (int i = 0; i < 8; ++i)
                *(float4*)&po[slot][lane][i * 4] = oacc[i];
        }
        __syncthreads();
        if (w < stride) {
            const float m2 = pm[w][lane];
            const float l2 = pl[w][lane];
            const float M  = fmaxf(mval, m2);
            const float e1 = __expf(mval - M);
            const float e2 = __expf(m2 - M);
            lsum = lsum * e1 + l2 * e2;
#pragma unroll
            for (int i = 0; i < 8; ++i) {
                const float4 p = *(const float4*)&po[w][lane][i * 4];
                oacc[i].x = oacc[i].x * e1 + p.x * e2;
                oacc[i].y = oacc[i].y * e1 + p.y * e2;
                oacc[i].z = oacc[i].z * e1 + p.z * e2;
                oacc[i].w = oacc[i].w * e1 + p.w * e2;
            }
            mval = M;
        }
        __syncthreads();
    }

    if (w == 0) {
        const float inv = 1.f / lsum;
        float4* op = (float4*)(o + ((size_t)(b * NN + r)) * DIMD + h * HD);
#pragma unroll
        for (int i = 0; i < 8; ++i) {
            float4 t = oacc[i];
            t.x *= inv; t.y *= inv; t.z *= inv; t.w *= inv;
            op[i] = t;
        }
    }
}

// ---------------------------------------------------------------------------
// Launch: only the LAST layer (i = DEPTH-1) matters — the reference never
// feeds `out` back into `x`, so earlier layers' outputs are discarded.
// ---------------------------------------------------------------------------
extern "C" void kernel_launch(void* const* d_in, const int* in_sizes, int n_in,
                              void* d_out, int out_size, void* d_ws, size_t ws_size,
                              hipStream_t stream)
{
    const int L = DEPTHC - 1;  // last layer only
    const float* x     = (const float*)d_in[0];
    const float* ln1_g = (const float*)d_in[1]  + L * DIMD;
    const float* ln1_b = (const float*)d_in[2]  + L * DIMD;
    const float* Wqkv  = (const float*)d_in[3]  + (size_t)L * DIMD * 3 * DIMD;
    const float* bqkv  = (const float*)d_in[4]  + L * 3 * DIMD;
    const float* Wo    = (const float*)d_in[5]  + (size_t)L * DIMD * DIMD;
    const float* bo    = (const float*)d_in[6]  + L * DIMD;
    const float* ln2_g = (const float*)d_in[7]  + L * DIMD;
    const float* ln2_b = (const float*)d_in[8]  + L * DIMD;
    const float* W1    = (const float*)d_in[9]  + (size_t)L * DIMD * MLPD;
    const float* b1    = (const float*)d_in[10] + L * MLPD;
    const float* W2    = (const float*)d_in[11] + (size_t)L * MLPD * DIMD;
    const float* b2    = (const float*)d_in[12] + L * DIMD;
    float* out = (float*)d_out;

    // Workspace layout (floats):
    float* y   = (float*)d_ws;                  // [4096,256]  (reused for z)
    float* qkv = y   + (size_t)ROWS * DIMD;     // [4096,768]
    float* o   = qkv + (size_t)ROWS * 3 * DIMD; // [4096,256]
    float* a   = o   + (size_t)ROWS * DIMD;     // [4096,256]
    float* m1  = a   + (size_t)ROWS * DIMD;     // [4096,1024]

    // 1) y = LN1(x)
    ln_kernel<<<ROWS / 4, 256, 0, stream>>>(x, ln1_g, ln1_b, y);

    // 2) qkv = y @ Wqkv + bqkv
    gemm64<false, false><<<dim3(3 * DIMD / 64, ROWS / 64), 256, 0, stream>>>(
        y, Wqkv, bqkv, nullptr, qkv, ROWS, 3 * DIMD, DIMD);

    // 3) o = attention(q, k, v)  — 8-way key-split per block
    attn_kernel<<<dim3(NN / 64, BB * HH), 512, 0, stream>>>(qkv, o);

    // 4) a = o @ Wo + bo + x
    gemm64<false, true><<<dim3(DIMD / 64, ROWS / 64), 256, 0, stream>>>(
        o, Wo, bo, x, a, ROWS, DIMD, DIMD);

    // 5) z = LN2(a)  (reuse y buffer)
    ln_kernel<<<ROWS / 4, 256, 0, stream>>>(a, ln2_g, ln2_b, y);

    // 6) m1 = gelu(z @ W1 + b1)
    gemm64<true, false><<<dim3(MLPD / 64, ROWS / 64), 256, 0, stream>>>(
        y, W1, b1, nullptr, m1, ROWS, MLPD, DIMD);

    // 7) out = m1 @ W2 + b2 + a
    gemm64<false, true><<<dim3(DIMD / 64, ROWS / 64), 256, 0, stream>>>(
        m1, W2, b2, a, out, ROWS, DIMD, MLPD);
}

// Round 3
// 292.615 us; speedup vs baseline: 3.5587x; 2.2809x over previous
//
#include <hip/hip_runtime.h>
#include <hip/hip_bf16.h>
#include <math.h>

// Problem constants (fixed by the reference).
#define DEPTHC 2
#define DIMD   256
#define MLPD   1024
#define BB     2
#define NN     2048
#define HH     8
#define HD     32
#define ROWS   (BB * NN)   // 4096 token rows

typedef __attribute__((ext_vector_type(8))) short bf16x8;
typedef __attribute__((ext_vector_type(4))) float f32x4;

// f32 -> bf16 bits, round-to-nearest-even.
__device__ __forceinline__ short f2bf(float x) {
    union { float f; unsigned u; } c; c.f = x;
    unsigned u = c.u + (0x7fffu + ((c.u >> 16) & 1u));
    return (short)(u >> 16);
}

// ---------------------------------------------------------------------------
// LayerNorm: one wave (64 lanes) per 256-element row; 4 rows per 256-thr block.
// ---------------------------------------------------------------------------
__global__ __launch_bounds__(256) void ln_kernel(
    const float* __restrict__ x, const float* __restrict__ g,
    const float* __restrict__ bta, float* __restrict__ y)
{
    const int wave = threadIdx.x >> 6;
    const int lane = threadIdx.x & 63;
    const int row  = blockIdx.x * 4 + wave;
    const float* xr = x + (size_t)row * DIMD;

    float v[4];
    float s = 0.f, sq = 0.f;
#pragma unroll
    for (int i = 0; i < 4; ++i) {
        v[i] = xr[lane + 64 * i];
        s  += v[i];
        sq += v[i] * v[i];
    }
#pragma unroll
    for (int off = 32; off > 0; off >>= 1) {
        s  += __shfl_down(s,  off, 64);
        sq += __shfl_down(sq, off, 64);
    }
    s  = __shfl(s,  0, 64);
    sq = __shfl(sq, 0, 64);

    const float mean = s * (1.f / DIMD);
    const float var  = sq * (1.f / DIMD) - mean * mean;
    const float rstd = rsqrtf(var + 1e-5f);

    float* yr = y + (size_t)row * DIMD;
#pragma unroll
    for (int i = 0; i < 4; ++i) {
        const int c = lane + 64 * i;
        yr[c] = (v[i] - mean) * rstd * g[c] + bta[c];
    }
}

// ---------------------------------------------------------------------------
// Generic f32 GEMM: C[M,N] = epilogue(A[M,K] @ W[K,N] + bias (+R) (gelu?))
// 64x64 tile, BK=16, 256 threads, 4x4 micro-tile per thread.
// ---------------------------------------------------------------------------
template <bool GELU, bool RES>
__global__ __launch_bounds__(256) void gemm64(
    const float* __restrict__ A, const float* __restrict__ W,
    const float* __restrict__ bias, const float* __restrict__ R,
    float* __restrict__ C, int M, int N, int K)
{
    __shared__ float As[16][64];   // transposed A tile: As[k][m]
    __shared__ float Ws[16][64];

    const int tid = threadIdx.x;
    const int m0  = blockIdx.y * 64;
    const int n0  = blockIdx.x * 64;

    const int am = tid >> 2;           // 0..63  (A tile row)
    const int ak = (tid & 3) << 2;     // 0,4,8,12
    const int wk = tid >> 4;           // 0..15  (W tile row)
    const int wn = (tid & 15) << 2;    // 0..60
    const int tm = (tid >> 4) << 2;    // micro-tile row base
    const int tn = (tid & 15) << 2;    // micro-tile col base

    float acc[4][4] = {};

    for (int k0 = 0; k0 < K; k0 += 16) {
        const float4 a4 = *(const float4*)&A[(size_t)(m0 + am) * K + k0 + ak];
        As[ak + 0][am] = a4.x;
        As[ak + 1][am] = a4.y;
        As[ak + 2][am] = a4.z;
        As[ak + 3][am] = a4.w;
        *(float4*)&Ws[wk][wn] = *(const float4*)&W[(size_t)(k0 + wk) * N + n0 + wn];
        __syncthreads();

#pragma unroll
        for (int kk = 0; kk < 16; ++kk) {
            const float4 a = *(const float4*)&As[kk][tm];
            const float4 w = *(const float4*)&Ws[kk][tn];
            const float av[4] = {a.x, a.y, a.z, a.w};
            const float wv[4] = {w.x, w.y, w.z, w.w};
#pragma unroll
            for (int i = 0; i < 4; ++i)
#pragma unroll
                for (int j = 0; j < 4; ++j)
                    acc[i][j] += av[i] * wv[j];
        }
        __syncthreads();
    }

#pragma unroll
    for (int i = 0; i < 4; ++i) {
        float4 outv;
        float* po = (float*)&outv;
        const size_t crow = (size_t)(m0 + tm + i) * N + n0 + tn;
#pragma unroll
        for (int j = 0; j < 4; ++j) {
            float vv = acc[i][j] + bias[n0 + tn + j];
            if (RES)  vv += R[crow + j];
            if (GELU) vv = 0.5f * vv * (1.f + erff(vv * 0.70710678118f));
            po[j] = vv;
        }
        *(float4*)&C[crow] = outv;
    }
}

// ---------------------------------------------------------------------------
// MFMA flash attention.
// Grid: (N/64 q-tiles, B*H). Block: 256 threads = 4 waves.
// Wave w owns 16 queries (one 16x16x32 A-frag: k = 32 = whole head dim).
// Per 64-key tile (staged cooperatively in LDS as bf16; V transposed):
//   S[16q x 64k] = 4 MFMAs; in-register online softmax (rows q = quad*4+reg,
//   reductions = xor-shuffles over the 16-lane column group);
//   P -> per-wave LDS tile (A-frag layout), PV = 4 MFMAs into O accumulator.
// LDS row pads (40/72 shorts) keep every b128 read at 2-way aliasing (free).
// ---------------------------------------------------------------------------
__global__ __launch_bounds__(256) void attn_mfma(
    const float* __restrict__ qkv, float* __restrict__ o)
{
    __shared__ short Ks[64][40];       // K tile: [key][d], 80B row stride
    __shared__ short Vt[32][72];       // V tile transposed: [d][key], 144B
    __shared__ short Ps[4][16][72];    // per-wave P: [q][key], 144B

    const int tid  = threadIdx.x;
    const int w    = tid >> 6;
    const int lane = tid & 63;
    const int quad = lane >> 4;
    const int l16  = lane & 15;
    const int bh   = blockIdx.y;
    const int b    = bh >> 3;
    const int h    = bh & 7;
    const int q0   = blockIdx.x * 64 + w * 16;   // wave's first query row

    const float scale = 0.17677669529663689f;    // 32^-0.5
    const float* base = qkv + (size_t)b * NN * (3 * DIMD);

    // Q A-frag: lane holds Q[q0+l16][quad*8 .. +7], pre-scaled, bf16.
    bf16x8 qfrag;
    {
        const float* qp = base + (size_t)(q0 + l16) * (3 * DIMD) + h * HD + quad * 8;
#pragma unroll
        for (int j = 0; j < 8; ++j) qfrag[j] = f2bf(qp[j] * scale);
    }

    f32x4 oacc0 = {0.f, 0.f, 0.f, 0.f};   // O[.., d = l16]
    f32x4 oacc1 = {0.f, 0.f, 0.f, 0.f};   // O[.., d = 16 + l16]
    float mreg[4] = {-1e30f, -1e30f, -1e30f, -1e30f};
    float lreg[4] = {0.f, 0.f, 0.f, 0.f};

    const int skey = tid >> 2;          // 0..63: staged key row
    const int sd   = (tid & 3) * 8;     // 0,8,16,24: staged dim base

#pragma unroll 1
    for (int t = 0; t < NN / 64; ++t) {
        __syncthreads();   // previous tile's LDS reads complete
        {
            const float* kp = base + (size_t)(t * 64 + skey) * (3 * DIMD) + DIMD + h * HD + sd;
            bf16x8 k8;
#pragma unroll
            for (int j = 0; j < 8; ++j) k8[j] = f2bf(kp[j]);
            *(bf16x8*)&Ks[skey][sd] = k8;
            const float* vp = kp + DIMD;   // V part
#pragma unroll
            for (int j = 0; j < 8; ++j) Vt[sd + j][skey] = f2bf(vp[j]);
        }
        __syncthreads();

        // S = Q @ K^T : 4 tiles of 16 keys
        f32x4 s[4];
#pragma unroll
        for (int kt = 0; kt < 4; ++kt) {
            const bf16x8 kf = *(const bf16x8*)&Ks[kt * 16 + l16][quad * 8];
            f32x4 z = {0.f, 0.f, 0.f, 0.f};
            s[kt] = __builtin_amdgcn_mfma_f32_16x16x32_bf16(qfrag, kf, z, 0, 0, 0);
        }

        // online softmax; rows q = quad*4 + r, cols spread over 16-lane group
        float mnew[4], alpha[4];
#pragma unroll
        for (int r = 0; r < 4; ++r) {
            float tmax = fmaxf(fmaxf(s[0][r], s[1][r]), fmaxf(s[2][r], s[3][r]));
#pragma unroll
            for (int off = 8; off >= 1; off >>= 1)
                tmax = fmaxf(tmax, __shfl_xor(tmax, off, 64));
            mnew[r]  = fmaxf(mreg[r], tmax);
            alpha[r] = __expf(mreg[r] - mnew[r]);
            mreg[r]  = mnew[r];
        }
        float rowsum[4] = {0.f, 0.f, 0.f, 0.f};
#pragma unroll
        for (int kt = 0; kt < 4; ++kt) {
#pragma unroll
            for (int r = 0; r < 4; ++r) {
                const float p = __expf(s[kt][r] - mnew[r]);
                rowsum[r] += p;
                Ps[w][quad * 4 + r][kt * 16 + l16] = f2bf(p);
            }
        }
#pragma unroll
        for (int r = 0; r < 4; ++r) {
            float rs = rowsum[r];
#pragma unroll
            for (int off = 8; off >= 1; off >>= 1)
                rs += __shfl_xor(rs, off, 64);
            lreg[r] = lreg[r] * alpha[r] + rs;
            oacc0[r] *= alpha[r];
            oacc1[r] *= alpha[r];
        }

        // O += P @ V : A = P[16q x 32key] chunks, B = V[32key x 16d] from Vt
#pragma unroll
        for (int c = 0; c < 2; ++c) {
            const bf16x8 pf = *(const bf16x8*)&Ps[w][l16][c * 32 + quad * 8];
            const bf16x8 v0 = *(const bf16x8*)&Vt[l16][c * 32 + quad * 8];
            const bf16x8 v1 = *(const bf16x8*)&Vt[16 + l16][c * 32 + quad * 8];
            oacc0 = __builtin_amdgcn_mfma_f32_16x16x32_bf16(pf, v0, oacc0, 0, 0, 0);
            oacc1 = __builtin_amdgcn_mfma_f32_16x16x32_bf16(pf, v1, oacc1, 0, 0, 0);
        }
    }

    // epilogue: O /= l, write f32
    float* op = o + ((size_t)(b * NN + q0)) * DIMD + h * HD;
#pragma unroll
    for (int r = 0; r < 4; ++r) {
        const float inv = 1.f / lreg[r];
        const size_t row = (size_t)(quad * 4 + r) * DIMD;
        op[row + l16]      = oacc0[r] * inv;
        op[row + 16 + l16] = oacc1[r] * inv;
    }
}

// ---------------------------------------------------------------------------
// Launch: only the LAST layer (i = DEPTH-1) matters — the reference never
// feeds `out` back into `x`, so earlier layers' outputs are discarded.
// ---------------------------------------------------------------------------
extern "C" void kernel_launch(void* const* d_in, const int* in_sizes, int n_in,
                              void* d_out, int out_size, void* d_ws, size_t ws_size,
                              hipStream_t stream)
{
    const int L = DEPTHC - 1;  // last layer only
    const float* x     = (const float*)d_in[0];
    const float* ln1_g = (const float*)d_in[1]  + L * DIMD;
    const float* ln1_b = (const float*)d_in[2]  + L * DIMD;
    const float* Wqkv  = (const float*)d_in[3]  + (size_t)L * DIMD * 3 * DIMD;
    const float* bqkv  = (const float*)d_in[4]  + L * 3 * DIMD;
    const float* Wo    = (const float*)d_in[5]  + (size_t)L * DIMD * DIMD;
    const float* bo    = (const float*)d_in[6]  + L * DIMD;
    const float* ln2_g = (const float*)d_in[7]  + L * DIMD;
    const float* ln2_b = (const float*)d_in[8]  + L * DIMD;
    const float* W1    = (const float*)d_in[9]  + (size_t)L * DIMD * MLPD;
    const float* b1    = (const float*)d_in[10] + L * MLPD;
    const float* W2    = (const float*)d_in[11] + (size_t)L * MLPD * DIMD;
    const float* b2    = (const float*)d_in[12] + L * DIMD;
    float* out = (float*)d_out;

    // Workspace layout (floats):
    float* y   = (float*)d_ws;                  // [4096,256]  (reused for z)
    float* qkv = y   + (size_t)ROWS * DIMD;     // [4096,768]
    float* o   = qkv + (size_t)ROWS * 3 * DIMD; // [4096,256]
    float* a   = o   + (size_t)ROWS * DIMD;     // [4096,256]
    float* m1  = a   + (size_t)ROWS * DIMD;     // [4096,1024]

    // 1) y = LN1(x)
    ln_kernel<<<ROWS / 4, 256, 0, stream>>>(x, ln1_g, ln1_b, y);

    // 2) qkv = y @ Wqkv + bqkv
    gemm64<false, false><<<dim3(3 * DIMD / 64, ROWS / 64), 256, 0, stream>>>(
        y, Wqkv, bqkv, nullptr, qkv, ROWS, 3 * DIMD, DIMD);

    // 3) o = attention(q, k, v)  — MFMA flash attention
    attn_mfma<<<dim3(NN / 64, BB * HH), 256, 0, stream>>>(qkv, o);

    // 4) a = o @ Wo + bo + x
    gemm64<false, true><<<dim3(DIMD / 64, ROWS / 64), 256, 0, stream>>>(
        o, Wo, bo, x, a, ROWS, DIMD, DIMD);

    // 5) z = LN2(a)  (reuse y buffer)
    ln_kernel<<<ROWS / 4, 256, 0, stream>>>(a, ln2_g, ln2_b, y);

    // 6) m1 = gelu(z @ W1 + b1)
    gemm64<true, false><<<dim3(MLPD / 64, ROWS / 64), 256, 0, stream>>>(
        y, W1, b1, nullptr, m1, ROWS, MLPD, DIMD);

    // 7) out = m1 @ W2 + b2 + a
    gemm64<false, true><<<dim3(DIMD / 64, ROWS / 64), 256, 0, stream>>>(
        m1, W2, b2, a, out, ROWS, DIMD, MLPD);
}

// Round 5
// 211.252 us; speedup vs baseline: 4.9293x; 1.3851x over previous
//
#include <hip/hip_runtime.h>
#include <hip/hip_bf16.h>
#include <math.h>

// Problem constants (fixed by the reference).
#define DEPTHC 2
#define DIMD   256
#define MLPD   1024
#define BB     2
#define NN     2048
#define HH     8
#define HD     32
#define ROWS   (BB * NN)   // 4096 token rows

typedef __attribute__((ext_vector_type(8))) short bf16x8;
typedef __attribute__((ext_vector_type(4))) float f32x4;

// f32 -> bf16 bits, round-to-nearest-even.
__device__ __forceinline__ short f2bf(float x) {
    union { float f; unsigned u; } c; c.f = x;
    unsigned u = c.u + (0x7fffu + ((c.u >> 16) & 1u));
    return (short)(u >> 16);
}

// ---------------------------------------------------------------------------
// Weight transpose + f32->bf16: W[K][N] -> Wt[N][K]. 32x32 LDS tiles,
// coalesced on both sides. Grid: (N/32, K/32), block 256.
// ---------------------------------------------------------------------------
__global__ __launch_bounds__(256) void transpose_w(
    const float* __restrict__ W, short* __restrict__ Wt, int K, int N)
{
    __shared__ float t[32][33];
    const int tx = threadIdx.x & 31;
    const int ty = threadIdx.x >> 5;       // 0..7
    const int n0 = blockIdx.x * 32;
    const int k0 = blockIdx.y * 32;
#pragma unroll
    for (int i = 0; i < 4; ++i)
        t[ty + 8 * i][tx] = W[(size_t)(k0 + ty + 8 * i) * N + n0 + tx];
    __syncthreads();
#pragma unroll
    for (int i = 0; i < 4; ++i)
        Wt[(size_t)(n0 + ty + 8 * i) * K + k0 + tx] = f2bf(t[tx][ty + 8 * i]);
}

// ---------------------------------------------------------------------------
// LayerNorm: one wave per 256-elem row (lane owns 4 consecutive cols),
// 4 rows per 256-thread block. f32 in, bf16 out.
// ---------------------------------------------------------------------------
__global__ __launch_bounds__(256) void ln_kernel(
    const float* __restrict__ x, const float* __restrict__ g,
    const float* __restrict__ bta, short* __restrict__ y)
{
    const int wave = threadIdx.x >> 6;
    const int lane = threadIdx.x & 63;
    const int row  = blockIdx.x * 4 + wave;
    const int c    = lane * 4;

    const float4 v = *(const float4*)&x[(size_t)row * DIMD + c];
    float s  = v.x + v.y + v.z + v.w;
    float sq = v.x * v.x + v.y * v.y + v.z * v.z + v.w * v.w;
#pragma unroll
    for (int off = 32; off > 0; off >>= 1) {
        s  += __shfl_down(s,  off, 64);
        sq += __shfl_down(sq, off, 64);
    }
    s  = __shfl(s,  0, 64);
    sq = __shfl(sq, 0, 64);

    const float mean = s * (1.f / DIMD);
    const float var  = sq * (1.f / DIMD) - mean * mean;
    const float rstd = rsqrtf(var + 1e-5f);

    const float4 gg = *(const float4*)&g[c];
    const float4 bb = *(const float4*)&bta[c];
    short4 ov;
    ov.x = f2bf((v.x - mean) * rstd * gg.x + bb.x);
    ov.y = f2bf((v.y - mean) * rstd * gg.y + bb.y);
    ov.z = f2bf((v.z - mean) * rstd * gg.z + bb.z);
    ov.w = f2bf((v.w - mean) * rstd * gg.w + bb.w);
    *(short4*)&y[(size_t)row * DIMD + c] = ov;
}

// ---------------------------------------------------------------------------
// bf16 MFMA GEMM: C[M,N] = epi(A[M,K] @ Wt[N,K]^T + bias (+R) (gelu?))
// 64x64 tile, BK=64, 256 thr = 4 waves, wave = 32x32 (2x2 16-tiles).
// LDS rows padded to 72 shorts: every b128 access is 2-way (free).
// Staging: each thread writes TWO 16B chunks per matrix (rows sr, sr+32) —
// 256 thr x 2 chunks x 8 shorts = full 64x64 coverage.
// ---------------------------------------------------------------------------
template <bool GELU, bool RES, bool OBF>
__global__ __launch_bounds__(256) void gemm_mfma(
    const short* __restrict__ A,   // [M][K] bf16
    const short* __restrict__ Wt,  // [N][K] bf16
    const float* __restrict__ bias,
    const float* __restrict__ R,
    void* __restrict__ Cv, int M, int N, int K)
{
    __shared__ short As[64][72];
    __shared__ short Bs[64][72];

    const int tid  = threadIdx.x;
    const int m0   = blockIdx.y * 64;
    const int n0   = blockIdx.x * 64;
    const int w    = tid >> 6;
    const int lane = tid & 63;
    const int quad = lane >> 4;
    const int l16  = lane & 15;
    const int wr   = (w >> 1) * 32;      // wave row offset in tile
    const int wc   = (w & 1) * 32;       // wave col offset in tile

    const int sr = tid >> 3;             // staging row 0..31 (and +32)
    const int sc = (tid & 7) * 8;        // staging col 0..56 step 8

    f32x4 acc[2][2] = {};

    for (int k0 = 0; k0 < K; k0 += 64) {
        __syncthreads();
        *(bf16x8*)&As[sr][sc]      = *(const bf16x8*)&A[(size_t)(m0 + sr) * K + k0 + sc];
        *(bf16x8*)&As[sr + 32][sc] = *(const bf16x8*)&A[(size_t)(m0 + sr + 32) * K + k0 + sc];
        *(bf16x8*)&Bs[sr][sc]      = *(const bf16x8*)&Wt[(size_t)(n0 + sr) * K + k0 + sc];
        *(bf16x8*)&Bs[sr + 32][sc] = *(const bf16x8*)&Wt[(size_t)(n0 + sr + 32) * K + k0 + sc];
        __syncthreads();

#pragma unroll
        for (int kc = 0; kc < 2; ++kc) {
            bf16x8 af[2], bfr[2];
#pragma unroll
            for (int i = 0; i < 2; ++i) {
                af[i]  = *(const bf16x8*)&As[wr + i * 16 + l16][kc * 32 + quad * 8];
                bfr[i] = *(const bf16x8*)&Bs[wc + i * 16 + l16][kc * 32 + quad * 8];
            }
#pragma unroll
            for (int i = 0; i < 2; ++i)
#pragma unroll
                for (int j = 0; j < 2; ++j)
                    acc[i][j] = __builtin_amdgcn_mfma_f32_16x16x32_bf16(
                        af[i], bfr[j], acc[i][j], 0, 0, 0);
        }
    }

#pragma unroll
    for (int i = 0; i < 2; ++i)
#pragma unroll
    for (int j = 0; j < 2; ++j)
#pragma unroll
    for (int r = 0; r < 4; ++r) {
        const int row = m0 + wr + i * 16 + quad * 4 + r;
        const int col = n0 + wc + j * 16 + l16;
        float v = acc[i][j][r] + bias[col];
        if (RES)  v += R[(size_t)row * N + col];
        if (GELU) v = 0.5f * v * (1.f + erff(v * 0.70710678118f));
        if (OBF) ((short*)Cv)[(size_t)row * N + col] = f2bf(v);
        else     ((float*)Cv)[(size_t)row * N + col] = v;
    }
}

// ---------------------------------------------------------------------------
// MFMA flash attention, bf16 qkv input, bf16 o output.
// Grid: (N/64 q-tiles, B*H). Block: 256 = 4 waves; wave owns 16 queries.
// Scale folded into post-MFMA S values.
// ---------------------------------------------------------------------------
__global__ __launch_bounds__(256) void attn_mfma(
    const short* __restrict__ qkv, short* __restrict__ o)
{
    __shared__ short Ks[64][40];       // [key][d]
    __shared__ short Vt[32][72];       // [d][key]
    __shared__ short Ps[4][16][72];    // per-wave P: [q][key]

    const int tid  = threadIdx.x;
    const int w    = tid >> 6;
    const int lane = tid & 63;
    const int quad = lane >> 4;
    const int l16  = lane & 15;
    const int bh   = blockIdx.y;
    const int b    = bh >> 3;
    const int h    = bh & 7;
    const int q0   = blockIdx.x * 64 + w * 16;

    const float scale = 0.17677669529663689f;    // 32^-0.5
    const short* base = qkv + (size_t)b * NN * (3 * DIMD);

    const bf16x8 qfrag =
        *(const bf16x8*)(base + (size_t)(q0 + l16) * (3 * DIMD) + h * HD + quad * 8);

    f32x4 oacc0 = {0.f, 0.f, 0.f, 0.f};
    f32x4 oacc1 = {0.f, 0.f, 0.f, 0.f};
    float mreg[4] = {-1e30f, -1e30f, -1e30f, -1e30f};
    float lreg[4] = {0.f, 0.f, 0.f, 0.f};

    const int skey = tid >> 2;
    const int sd   = (tid & 3) * 8;

#pragma unroll 1
    for (int t = 0; t < NN / 64; ++t) {
        __syncthreads();
        {
            const short* kp = base + (size_t)(t * 64 + skey) * (3 * DIMD) + DIMD + h * HD + sd;
            *(bf16x8*)&Ks[skey][sd] = *(const bf16x8*)kp;
            const short* vp = kp + DIMD;
#pragma unroll
            for (int j = 0; j < 8; ++j) Vt[sd + j][skey] = vp[j];
        }
        __syncthreads();

        // S = Q @ K^T
        f32x4 s[4];
#pragma unroll
        for (int kt = 0; kt < 4; ++kt) {
            const bf16x8 kf = *(const bf16x8*)&Ks[kt * 16 + l16][quad * 8];
            f32x4 z = {0.f, 0.f, 0.f, 0.f};
            s[kt] = __builtin_amdgcn_mfma_f32_16x16x32_bf16(qfrag, kf, z, 0, 0, 0);
#pragma unroll
            for (int r = 0; r < 4; ++r) s[kt][r] *= scale;
        }

        // online softmax
        float mnew[4], alpha[4];
#pragma unroll
        for (int r = 0; r < 4; ++r) {
            float tmax = fmaxf(fmaxf(s[0][r], s[1][r]), fmaxf(s[2][r], s[3][r]));
#pragma unroll
            for (int off = 8; off >= 1; off >>= 1)
                tmax = fmaxf(tmax, __shfl_xor(tmax, off, 64));
            mnew[r]  = fmaxf(mreg[r], tmax);
            alpha[r] = __expf(mreg[r] - mnew[r]);
            mreg[r]  = mnew[r];
        }
        float rowsum[4] = {0.f, 0.f, 0.f, 0.f};
#pragma unroll
        for (int kt = 0; kt < 4; ++kt) {
#pragma unroll
            for (int r = 0; r < 4; ++r) {
                const float p = __expf(s[kt][r] - mnew[r]);
                rowsum[r] += p;
                Ps[w][quad * 4 + r][kt * 16 + l16] = f2bf(p);
            }
        }
#pragma unroll
        for (int r = 0; r < 4; ++r) {
            float rs = rowsum[r];
#pragma unroll
            for (int off = 8; off >= 1; off >>= 1)
                rs += __shfl_xor(rs, off, 64);
            lreg[r] = lreg[r] * alpha[r] + rs;
            oacc0[r] *= alpha[r];
            oacc1[r] *= alpha[r];
        }

        // O += P @ V
#pragma unroll
        for (int c = 0; c < 2; ++c) {
            const bf16x8 pf = *(const bf16x8*)&Ps[w][l16][c * 32 + quad * 8];
            const bf16x8 v0 = *(const bf16x8*)&Vt[l16][c * 32 + quad * 8];
            const bf16x8 v1 = *(const bf16x8*)&Vt[16 + l16][c * 32 + quad * 8];
            oacc0 = __builtin_amdgcn_mfma_f32_16x16x32_bf16(pf, v0, oacc0, 0, 0, 0);
            oacc1 = __builtin_amdgcn_mfma_f32_16x16x32_bf16(pf, v1, oacc1, 0, 0, 0);
        }
    }

    short* op = o + ((size_t)(b * NN + q0)) * DIMD + h * HD;
#pragma unroll
    for (int r = 0; r < 4; ++r) {
        const float inv = 1.f / lreg[r];
        const size_t row = (size_t)(quad * 4 + r) * DIMD;
        op[row + l16]      = f2bf(oacc0[r] * inv);
        op[row + 16 + l16] = f2bf(oacc1[r] * inv);
    }
}

// ---------------------------------------------------------------------------
// Launch: only the LAST layer (i = DEPTH-1) matters — the reference never
// feeds `out` back into `x`, so earlier layers' outputs are discarded.
// ---------------------------------------------------------------------------
extern "C" void kernel_launch(void* const* d_in, const int* in_sizes, int n_in,
                              void* d_out, int out_size, void* d_ws, size_t ws_size,
                              hipStream_t stream)
{
    const int L = DEPTHC - 1;  // last layer only
    const float* x     = (const float*)d_in[0];
    const float* ln1_g = (const float*)d_in[1]  + L * DIMD;
    const float* ln1_b = (const float*)d_in[2]  + L * DIMD;
    const float* Wqkv  = (const float*)d_in[3]  + (size_t)L * DIMD * 3 * DIMD;
    const float* bqkv  = (const float*)d_in[4]  + L * 3 * DIMD;
    const float* Wo    = (const float*)d_in[5]  + (size_t)L * DIMD * DIMD;
    const float* bo    = (const float*)d_in[6]  + L * DIMD;
    const float* ln2_g = (const float*)d_in[7]  + L * DIMD;
    const float* ln2_b = (const float*)d_in[8]  + L * DIMD;
    const float* W1    = (const float*)d_in[9]  + (size_t)L * DIMD * MLPD;
    const float* b1    = (const float*)d_in[10] + L * MLPD;
    const float* W2    = (const float*)d_in[11] + (size_t)L * MLPD * DIMD;
    const float* b2    = (const float*)d_in[12] + L * DIMD;
    float* out = (float*)d_out;

    // Workspace layout (all 16B-aligned by construction):
    short* WqkvT = (short*)d_ws;                         // [768][256]
    short* WoT   = WqkvT + 768 * 256;                    // [256][256]
    short* W1T   = WoT   + 256 * 256;                    // [1024][256]
    short* W2T   = W1T   + 1024 * 256;                   // [256][1024]
    short* ybf   = W2T   + 256 * 1024;                   // [4096][256] (y, then z)
    short* qkvbf = ybf   + (size_t)ROWS * DIMD;          // [4096][768]
    short* obf   = qkvbf + (size_t)ROWS * 3 * DIMD;      // [4096][256]
    float* a     = (float*)(obf + (size_t)ROWS * DIMD);  // [4096][256] f32
    short* m1bf  = (short*)(a + (size_t)ROWS * DIMD);    // [4096][1024]

    // 0) weight transpose + bf16 convert (per-launch, ~0.8M elems total)
    transpose_w<<<dim3(3 * DIMD / 32, DIMD / 32), 256, 0, stream>>>(Wqkv, WqkvT, DIMD, 3 * DIMD);
    transpose_w<<<dim3(DIMD / 32,     DIMD / 32), 256, 0, stream>>>(Wo,   WoT,   DIMD, DIMD);
    transpose_w<<<dim3(MLPD / 32,     DIMD / 32), 256, 0, stream>>>(W1,   W1T,   DIMD, MLPD);
    transpose_w<<<dim3(DIMD / 32,     MLPD / 32), 256, 0, stream>>>(W2,   W2T,   MLPD, DIMD);

    // 1) y = LN1(x)                       (bf16 out)
    ln_kernel<<<ROWS / 4, 256, 0, stream>>>(x, ln1_g, ln1_b, ybf);

    // 2) qkv = y @ Wqkv + bqkv            (bf16 out)
    gemm_mfma<false, false, true><<<dim3(3 * DIMD / 64, ROWS / 64), 256, 0, stream>>>(
        ybf, WqkvT, bqkv, nullptr, qkvbf, ROWS, 3 * DIMD, DIMD);

    // 3) o = attention(q, k, v)           (bf16 out)
    attn_mfma<<<dim3(NN / 64, BB * HH), 256, 0, stream>>>(qkvbf, obf);

    // 4) a = o @ Wo + bo + x              (f32 out)
    gemm_mfma<false, true, false><<<dim3(DIMD / 64, ROWS / 64), 256, 0, stream>>>(
        obf, WoT, bo, x, a, ROWS, DIMD, DIMD);

    // 5) z = LN2(a)                       (bf16 out, reuse ybf)
    ln_kernel<<<ROWS / 4, 256, 0, stream>>>(a, ln2_g, ln2_b, ybf);

    // 6) m1 = gelu(z @ W1 + b1)           (bf16 out)
    gemm_mfma<true, false, true><<<dim3(MLPD / 64, ROWS / 64), 256, 0, stream>>>(
        ybf, W1T, b1, nullptr, m1bf, ROWS, MLPD, DIMD);

    // 7) out = m1 @ W2 + b2 + a           (f32 out)
    gemm_mfma<false, true, false><<<dim3(DIMD / 64, ROWS / 64), 256, 0, stream>>>(
        m1bf, W2T, b2, a, out, ROWS, DIMD, MLPD);
}

// Round 6
// 205.848 us; speedup vs baseline: 5.0587x; 1.0263x over previous
//
#include <hip/hip_runtime.h>
#include <hip/hip_bf16.h>
#include <math.h>

// Problem constants (fixed by the reference).
#define DEPTHC 2
#define DIMD   256
#define MLPD   1024
#define BB     2
#define NN     2048
#define HH     8
#define HD     32
#define ROWS   (BB * NN)   // 4096 token rows
#define KSPLIT 4

typedef __attribute__((ext_vector_type(8))) short bf16x8;
typedef __attribute__((ext_vector_type(4))) float f32x4;

// f32 -> bf16 bits, round-to-nearest-even.
__device__ __forceinline__ short f2bf(float x) {
    union { float f; unsigned u; } c; c.f = x;
    unsigned u = c.u + (0x7fffu + ((c.u >> 16) & 1u));
    return (short)(u >> 16);
}
__device__ __forceinline__ float bf2f(short s) {
    union { unsigned u; float f; } c; c.u = ((unsigned)(unsigned short)s) << 16;
    return c.f;
}

// ---------------------------------------------------------------------------
// Weight transpose + f32->bf16: W[K][N] -> Wt[N][K]. 32x32 LDS tiles.
// ---------------------------------------------------------------------------
__global__ __launch_bounds__(256) void transpose_w(
    const float* __restrict__ W, short* __restrict__ Wt, int K, int N)
{
    __shared__ float t[32][33];
    const int tx = threadIdx.x & 31;
    const int ty = threadIdx.x >> 5;       // 0..7
    const int n0 = blockIdx.x * 32;
    const int k0 = blockIdx.y * 32;
#pragma unroll
    for (int i = 0; i < 4; ++i)
        t[ty + 8 * i][tx] = W[(size_t)(k0 + ty + 8 * i) * N + n0 + tx];
    __syncthreads();
#pragma unroll
    for (int i = 0; i < 4; ++i)
        Wt[(size_t)(n0 + ty + 8 * i) * K + k0 + tx] = f2bf(t[tx][ty + 8 * i]);
}

// ---------------------------------------------------------------------------
// V transpose into global: qkv[b][n][512+h*32+d] -> vtg[bh][d][n] (bf16).
// Grid: (NN/64, 16 bh). One-time pass, 1M elems.
// ---------------------------------------------------------------------------
__global__ __launch_bounds__(256) void transpose_v(
    const short* __restrict__ qkv, short* __restrict__ vtg)
{
    __shared__ short Vs[64][33];
    const int tid = threadIdx.x;
    const int bh  = blockIdx.y;
    const int b   = bh >> 3;
    const int h   = bh & 7;
    const int n0  = blockIdx.x * 64;

    const int kk = tid >> 2;             // 0..63 key
    const int sd = (tid & 3) * 8;        // dim base
    const bf16x8 tmp = *(const bf16x8*)(
        qkv + ((size_t)(b * NN + n0 + kk)) * (3 * DIMD) + 2 * DIMD + h * HD + sd);
#pragma unroll
    for (int j = 0; j < 8; ++j) Vs[kk][sd + j] = tmp[j];
    __syncthreads();

    const int d  = tid >> 3;             // 0..31 dim
    const int kc = (tid & 7) * 8;        // key base
    bf16x8 v;
#pragma unroll
    for (int j = 0; j < 8; ++j) v[j] = Vs[kc + j][d];
    *(bf16x8*)&vtg[((size_t)(bh * HD + d)) * NN + n0 + kc] = v;
}

// ---------------------------------------------------------------------------
// LayerNorm: one wave per 256-elem row, 4 rows/block. f32 in, bf16 out.
// ---------------------------------------------------------------------------
__global__ __launch_bounds__(256) void ln_kernel(
    const float* __restrict__ x, const float* __restrict__ g,
    const float* __restrict__ bta, short* __restrict__ y)
{
    const int wave = threadIdx.x >> 6;
    const int lane = threadIdx.x & 63;
    const int row  = blockIdx.x * 4 + wave;
    const int c    = lane * 4;

    const float4 v = *(const float4*)&x[(size_t)row * DIMD + c];
    float s  = v.x + v.y + v.z + v.w;
    float sq = v.x * v.x + v.y * v.y + v.z * v.z + v.w * v.w;
#pragma unroll
    for (int off = 32; off > 0; off >>= 1) {
        s  += __shfl_down(s,  off, 64);
        sq += __shfl_down(sq, off, 64);
    }
    s  = __shfl(s,  0, 64);
    sq = __shfl(sq, 0, 64);

    const float mean = s * (1.f / DIMD);
    const float var  = sq * (1.f / DIMD) - mean * mean;
    const float rstd = rsqrtf(var + 1e-5f);

    const float4 gg = *(const float4*)&g[c];
    const float4 bb = *(const float4*)&bta[c];
    short4 ov;
    ov.x = f2bf((v.x - mean) * rstd * gg.x + bb.x);
    ov.y = f2bf((v.y - mean) * rstd * gg.y + bb.y);
    ov.z = f2bf((v.z - mean) * rstd * gg.z + bb.z);
    ov.w = f2bf((v.w - mean) * rstd * gg.w + bb.w);
    *(short4*)&y[(size_t)row * DIMD + c] = ov;
}

// ---------------------------------------------------------------------------
// bf16 MFMA GEMM: C[M,N] = epi(A[M,K] @ Wt[N,K]^T + bias (+R) (gelu?))
// 64x64 tile, BK=64, 256 thr = 4 waves, wave = 32x32 (2x2 16-tiles).
// ---------------------------------------------------------------------------
template <bool GELU, bool RES, bool OBF>
__global__ __launch_bounds__(256) void gemm_mfma(
    const short* __restrict__ A,   // [M][K] bf16
    const short* __restrict__ Wt,  // [N][K] bf16
    const float* __restrict__ bias,
    const float* __restrict__ R,
    void* __restrict__ Cv, int M, int N, int K)
{
    __shared__ short As[64][72];
    __shared__ short Bs[64][72];

    const int tid  = threadIdx.x;
    const int m0   = blockIdx.y * 64;
    const int n0   = blockIdx.x * 64;
    const int w    = tid >> 6;
    const int lane = tid & 63;
    const int quad = lane >> 4;
    const int l16  = lane & 15;
    const int wr   = (w >> 1) * 32;
    const int wc   = (w & 1) * 32;

    const int sr = tid >> 3;             // 0..31 (and +32)
    const int sc = (tid & 7) * 8;        // 0..56 step 8

    f32x4 acc[2][2] = {};

    for (int k0 = 0; k0 < K; k0 += 64) {
        __syncthreads();
        *(bf16x8*)&As[sr][sc]      = *(const bf16x8*)&A[(size_t)(m0 + sr) * K + k0 + sc];
        *(bf16x8*)&As[sr + 32][sc] = *(const bf16x8*)&A[(size_t)(m0 + sr + 32) * K + k0 + sc];
        *(bf16x8*)&Bs[sr][sc]      = *(const bf16x8*)&Wt[(size_t)(n0 + sr) * K + k0 + sc];
        *(bf16x8*)&Bs[sr + 32][sc] = *(const bf16x8*)&Wt[(size_t)(n0 + sr + 32) * K + k0 + sc];
        __syncthreads();

#pragma unroll
        for (int kc = 0; kc < 2; ++kc) {
            bf16x8 af[2], bfr[2];
#pragma unroll
            for (int i = 0; i < 2; ++i) {
                af[i]  = *(const bf16x8*)&As[wr + i * 16 + l16][kc * 32 + quad * 8];
                bfr[i] = *(const bf16x8*)&Bs[wc + i * 16 + l16][kc * 32 + quad * 8];
            }
#pragma unroll
            for (int i = 0; i < 2; ++i)
#pragma unroll
                for (int j = 0; j < 2; ++j)
                    acc[i][j] = __builtin_amdgcn_mfma_f32_16x16x32_bf16(
                        af[i], bfr[j], acc[i][j], 0, 0, 0);
        }
    }

#pragma unroll
    for (int i = 0; i < 2; ++i)
#pragma unroll
    for (int j = 0; j < 2; ++j)
#pragma unroll
    for (int r = 0; r < 4; ++r) {
        const int row = m0 + wr + i * 16 + quad * 4 + r;
        const int col = n0 + wc + j * 16 + l16;
        float v = acc[i][j][r] + bias[col];
        if (RES)  v += R[(size_t)row * N + col];
        if (GELU) v = 0.5f * v * (1.f + erff(v * 0.70710678118f));
        if (OBF) ((short*)Cv)[(size_t)row * N + col] = f2bf(v);
        else     ((float*)Cv)[(size_t)row * N + col] = v;
    }
}

// ---------------------------------------------------------------------------
// MFMA flash attention, 4-way key-split.
// Grid: (32 q-tiles, 16 bh, 4 ks). Block: 256 = 4 waves; wave owns 16 queries,
// block processes keys [ks*512, ks*512+512) in 64-key LDS tiles.
// Emits UNNORMALIZED partial O (bf16) + per-row (m, l) to workspace.
// V comes pre-transposed from vtg[bh][d][n] (conflict-free staging).
// ---------------------------------------------------------------------------
__global__ __launch_bounds__(256) void attn_mfma(
    const short* __restrict__ qkv, const short* __restrict__ vtg,
    short* __restrict__ pO, float* __restrict__ pm, float* __restrict__ pl)
{
    __shared__ short Ks[64][40];       // [key][d]
    __shared__ short Vs[32][72];       // [d][key]
    __shared__ short Ps[4][16][72];    // per-wave P: [q][key]

    const int tid  = threadIdx.x;
    const int w    = tid >> 6;
    const int lane = tid & 63;
    const int quad = lane >> 4;
    const int l16  = lane & 15;
    const int bh   = blockIdx.y;
    const int b    = bh >> 3;
    const int h    = bh & 7;
    const int ks   = blockIdx.z;
    const int q0   = blockIdx.x * 64 + w * 16;

    const float scale = 0.17677669529663689f;    // 32^-0.5
    const short* base = qkv + (size_t)b * NN * (3 * DIMD);

    const bf16x8 qfrag =
        *(const bf16x8*)(base + (size_t)(q0 + l16) * (3 * DIMD) + h * HD + quad * 8);

    f32x4 oacc0 = {0.f, 0.f, 0.f, 0.f};
    f32x4 oacc1 = {0.f, 0.f, 0.f, 0.f};
    float mreg[4] = {-1e30f, -1e30f, -1e30f, -1e30f};
    float lreg[4] = {0.f, 0.f, 0.f, 0.f};

    const int skey = tid >> 2;           // K staging: key 0..63
    const int sd   = (tid & 3) * 8;      //            dim base
    const int vd   = tid >> 3;           // V staging: dim 0..31
    const int vk   = (tid & 7) * 8;      //            key base

#pragma unroll 1
    for (int t = ks * (NN / KSPLIT / 64); t < (ks + 1) * (NN / KSPLIT / 64); ++t) {
        __syncthreads();
        *(bf16x8*)&Ks[skey][sd] = *(const bf16x8*)(
            base + (size_t)(t * 64 + skey) * (3 * DIMD) + DIMD + h * HD + sd);
        *(bf16x8*)&Vs[vd][vk] = *(const bf16x8*)(
            vtg + ((size_t)(bh * HD + vd)) * NN + t * 64 + vk);
        __syncthreads();

        // S = Q @ K^T
        f32x4 s[4];
#pragma unroll
        for (int kt = 0; kt < 4; ++kt) {
            const bf16x8 kf = *(const bf16x8*)&Ks[kt * 16 + l16][quad * 8];
            f32x4 z = {0.f, 0.f, 0.f, 0.f};
            s[kt] = __builtin_amdgcn_mfma_f32_16x16x32_bf16(qfrag, kf, z, 0, 0, 0);
#pragma unroll
            for (int r = 0; r < 4; ++r) s[kt][r] *= scale;
        }

        // online softmax
        float mnew[4], alpha[4];
#pragma unroll
        for (int r = 0; r < 4; ++r) {
            float tmax = fmaxf(fmaxf(s[0][r], s[1][r]), fmaxf(s[2][r], s[3][r]));
#pragma unroll
            for (int off = 8; off >= 1; off >>= 1)
                tmax = fmaxf(tmax, __shfl_xor(tmax, off, 64));
            mnew[r]  = fmaxf(mreg[r], tmax);
            alpha[r] = __expf(mreg[r] - mnew[r]);
            mreg[r]  = mnew[r];
        }
        float rowsum[4] = {0.f, 0.f, 0.f, 0.f};
#pragma unroll
        for (int kt = 0; kt < 4; ++kt) {
#pragma unroll
            for (int r = 0; r < 4; ++r) {
                const float p = __expf(s[kt][r] - mnew[r]);
                rowsum[r] += p;
                Ps[w][quad * 4 + r][kt * 16 + l16] = f2bf(p);
            }
        }
#pragma unroll
        for (int r = 0; r < 4; ++r) {
            float rs = rowsum[r];
#pragma unroll
            for (int off = 8; off >= 1; off >>= 1)
                rs += __shfl_xor(rs, off, 64);
            lreg[r] = lreg[r] * alpha[r] + rs;
            oacc0[r] *= alpha[r];
            oacc1[r] *= alpha[r];
        }

        // O += P @ V
#pragma unroll
        for (int c = 0; c < 2; ++c) {
            const bf16x8 pf = *(const bf16x8*)&Ps[w][l16][c * 32 + quad * 8];
            const bf16x8 v0 = *(const bf16x8*)&Vs[l16][c * 32 + quad * 8];
            const bf16x8 v1 = *(const bf16x8*)&Vs[16 + l16][c * 32 + quad * 8];
            oacc0 = __builtin_amdgcn_mfma_f32_16x16x32_bf16(pf, v0, oacc0, 0, 0, 0);
            oacc1 = __builtin_amdgcn_mfma_f32_16x16x32_bf16(pf, v1, oacc1, 0, 0, 0);
        }
    }

    // write unnormalized partials
#pragma unroll
    for (int r = 0; r < 4; ++r) {
        const size_t rg = (size_t)bh * NN + q0 + quad * 4 + r;
        pO[(rg * KSPLIT + ks) * HD + l16]      = f2bf(oacc0[r]);
        pO[(rg * KSPLIT + ks) * HD + 16 + l16] = f2bf(oacc1[r]);
        if (l16 == 0) {
            pm[rg * KSPLIT + ks] = mreg[r];
            pl[rg * KSPLIT + ks] = lreg[r];
        }
    }
}

// ---------------------------------------------------------------------------
// Merge the KSPLIT partials: standard (m,l) rescale combine. One thread per
// output element (32768 rows x 32 dims).
// ---------------------------------------------------------------------------
__global__ __launch_bounds__(256) void attn_merge(
    const short* __restrict__ pO, const float* __restrict__ pm,
    const float* __restrict__ pl, short* __restrict__ o)
{
    const int idx = blockIdx.x * 256 + threadIdx.x;
    const int r   = idx >> 5;          // global (bh, q) row
    const int d   = idx & 31;

    float m[KSPLIT];
#pragma unroll
    for (int s = 0; s < KSPLIT; ++s) m[s] = pm[r * KSPLIT + s];
    float M = fmaxf(fmaxf(m[0], m[1]), fmaxf(m[2], m[3]));
    float L = 0.f, O = 0.f;
#pragma unroll
    for (int s = 0; s < KSPLIT; ++s) {
        const float ww = __expf(m[s] - M);
        L += ww * pl[r * KSPLIT + s];
        O += ww * bf2f(pO[(size_t)(r * KSPLIT + s) * HD + d]);
    }
    const int bh = r >> 11;
    const int q  = r & (NN - 1);
    const int b  = bh >> 3;
    const int h  = bh & 7;
    o[((size_t)(b * NN + q)) * DIMD + h * HD + d] = f2bf(O / L);
}

// ---------------------------------------------------------------------------
// Launch: only the LAST layer (i = DEPTH-1) matters — the reference never
// feeds `out` back into `x`, so earlier layers' outputs are discarded.
// ---------------------------------------------------------------------------
extern "C" void kernel_launch(void* const* d_in, const int* in_sizes, int n_in,
                              void* d_out, int out_size, void* d_ws, size_t ws_size,
                              hipStream_t stream)
{
    const int L = DEPTHC - 1;  // last layer only
    const float* x     = (const float*)d_in[0];
    const float* ln1_g = (const float*)d_in[1]  + L * DIMD;
    const float* ln1_b = (const float*)d_in[2]  + L * DIMD;
    const float* Wqkv  = (const float*)d_in[3]  + (size_t)L * DIMD * 3 * DIMD;
    const float* bqkv  = (const float*)d_in[4]  + L * 3 * DIMD;
    const float* Wo    = (const float*)d_in[5]  + (size_t)L * DIMD * DIMD;
    const float* bo    = (const float*)d_in[6]  + L * DIMD;
    const float* ln2_g = (const float*)d_in[7]  + L * DIMD;
    const float* ln2_b = (const float*)d_in[8]  + L * DIMD;
    const float* W1    = (const float*)d_in[9]  + (size_t)L * DIMD * MLPD;
    const float* b1    = (const float*)d_in[10] + L * MLPD;
    const float* W2    = (const float*)d_in[11] + (size_t)L * MLPD * DIMD;
    const float* b2    = (const float*)d_in[12] + L * DIMD;
    float* out = (float*)d_out;

    // Workspace layout (aliases verified stream-order safe):
    short* WqkvT = (short*)d_ws;                         // [768][256]
    short* WoT   = WqkvT + 768 * 256;                    // [256][256]
    short* W1T   = WoT   + 256 * 256;                    // [1024][256]
    short* W2T   = W1T   + 1024 * 256;                   // [256][1024]
    short* ybf   = W2T   + 256 * 1024;                   // [4096][256] (y; then VtG; then z)
    short* qkvbf = ybf   + (size_t)ROWS * DIMD;          // [4096][768]
    short* obf   = qkvbf + (size_t)ROWS * 3 * DIMD;      // [4096][256]
    float* a     = (float*)(obf + (size_t)ROWS * DIMD);  // [4096][256] f32 (pm/pl first)
    short* m1bf  = (short*)(a + (size_t)ROWS * DIMD);    // [4096][1024] (pO first)

    short* vtg = ybf;                                    // alias: [16][32][2048]
    short* pO  = m1bf;                                   // alias: [32768][4][32]
    float* pm  = a;                                      // [32768][4]
    float* pl  = a + 32768 * KSPLIT;                     // [32768][4]

    // 0) weight transpose + bf16 convert
    transpose_w<<<dim3(3 * DIMD / 32, DIMD / 32), 256, 0, stream>>>(Wqkv, WqkvT, DIMD, 3 * DIMD);
    transpose_w<<<dim3(DIMD / 32,     DIMD / 32), 256, 0, stream>>>(Wo,   WoT,   DIMD, DIMD);
    transpose_w<<<dim3(MLPD / 32,     DIMD / 32), 256, 0, stream>>>(W1,   W1T,   DIMD, MLPD);
    transpose_w<<<dim3(DIMD / 32,     MLPD / 32), 256, 0, stream>>>(W2,   W2T,   MLPD, DIMD);

    // 1) y = LN1(x)                       (bf16 out -> ybf)
    ln_kernel<<<ROWS / 4, 256, 0, stream>>>(x, ln1_g, ln1_b, ybf);

    // 2) qkv = y @ Wqkv + bqkv            (bf16 out)
    gemm_mfma<false, false, true><<<dim3(3 * DIMD / 64, ROWS / 64), 256, 0, stream>>>(
        ybf, WqkvT, bqkv, nullptr, qkvbf, ROWS, 3 * DIMD, DIMD);

    // 2.5) V transpose into vtg (overwrites y — safe, y consumed by step 2)
    transpose_v<<<dim3(NN / 64, BB * HH), 256, 0, stream>>>(qkvbf, vtg);

    // 3) attention partials (4-way key split) + merge -> obf
    attn_mfma<<<dim3(NN / 64, BB * HH, KSPLIT), 256, 0, stream>>>(qkvbf, vtg, pO, pm, pl);
    attn_merge<<<(ROWS * HH * HD * KSPLIT / KSPLIT) / 256, 256, 0, stream>>>(pO, pm, pl, obf);

    // 4) a = o @ Wo + bo + x              (f32 out; overwrites pm/pl — safe)
    gemm_mfma<false, true, false><<<dim3(DIMD / 64, ROWS / 64), 256, 0, stream>>>(
        obf, WoT, bo, x, a, ROWS, DIMD, DIMD);

    // 5) z = LN2(a)                       (bf16 out -> ybf; overwrites vtg — safe)
    ln_kernel<<<ROWS / 4, 256, 0, stream>>>(a, ln2_g, ln2_b, ybf);

    // 6) m1 = gelu(z @ W1 + b1)           (bf16 out; overwrites pO — safe)
    gemm_mfma<true, false, true><<<dim3(MLPD / 64, ROWS / 64), 256, 0, stream>>>(
        ybf, W1T, b1, nullptr, m1bf, ROWS, MLPD, DIMD);

    // 7) out = m1 @ W2 + b2 + a           (f32 out)
    gemm_mfma<false, true, false><<<dim3(DIMD / 64, ROWS / 64), 256, 0, stream>>>(
        m1bf, W2T, b2, a, out, ROWS, DIMD, MLPD);
}